// Round 7
// baseline (46003.629 us; speedup 1.0000x reference)
//
#include <hip/hip_runtime.h>
#include <hip/hip_bf16.h>

// IEBins forward, fp64 math throughout (iter-0 label compare sits on a
// knife edge; fp32 accumulation flips it — round 2). Round 7:
//   - q-conv split: q = conv_h(rgh) + conv_x(x); conv_x folded into the
//     z/r kernel (shares the 448-ch d4/ctx loads -> 48 FMA per 2 loads);
//     q kernel shrinks to 128 channels (4.5x less work+loads).
//   - contiguous-slab XCD swizzle: same tile's out-ch groups adjacent ids
//     (co-resident, same XCD) AND consecutive tiles per XCD -> vertical /
//     3x3 tap row overlap now hits L2 (round-6 swizzle spaced tiles 8
//     apart -> 584 MB FETCH vs 183 ideal).
//   - z/r accumulation chains unchanged; q chain reordered (x-part then
//     h-part) — 1e-15-scale rounding delta, measure-zero flip risk.

#define HD  128
#define CDC 192
#define BN  16
#define OCH 256
#define GC  576
#define NB  2
#define HH  120
#define WW  160
#define HW  (HH*WW)
#define BHW (NB*HW)
#define PXT (BHW/128)          // 300 pixel tiles of 128 px
#define GXP (((PXT+7)/8)*8)    // 304 padded
#define TPX (GXP/8)            // 38 tiles per XCD slab

// ---------------------------------------------------------------- init ----
__global__ __launch_bounds__(256) void k_init(const float* __restrict__ gh,
        double* __restrict__ h, double* __restrict__ edges, double* __restrict__ cd){
  const int i = blockIdx.x*256 + threadIdx.x;
  const int nh = NB*HD*HW;
  if (i < nh) h[i] = (double)gh[i];
  if (i < BHW){
    const int b = i / HW, r = i - b*HW;
    double e = 0.0;
    #pragma unroll
    for (int k=0;k<BN;++k){
      edges[(b*(BN+1)+k)*HW + r] = e;
      cd[(b*BN+k)*HW + r] = e + 2.5;
      e += 5.0;
    }
    edges[(b*(BN+1)+BN)*HW + r] = e;   // 80
  }
}

// ------------------------------------------------- weight transpose ------
// w[o][c][tap] f32  ->  wt[(c*TAPS+t)*Cout + o] f64
__global__ __launch_bounds__(256) void k_wxpose(const float* __restrict__ w,
        double* __restrict__ wt, const int Cout, const int CIN, const int TAPS,
        const int n){
  const int i = blockIdx.x*256 + threadIdx.x;
  if (i >= n) return;
  const int ct = CIN*TAPS;
  const int o = i / ct;
  const int rem = i - o*ct;
  const int c = rem / TAPS;
  const int t = rem - c*TAPS;
  wt[((size_t)c*TAPS + t)*Cout + o] = (double)w[i];
}

// ------------------------------------------- XCD-aware block decode ------
// Grid = GXP*GY (1-D). id%8 -> XCD. Within an XCD: y-groups of one tile
// are adjacent (co-resident), tiles are consecutive (L2 row reuse).
template<int GY>
__device__ __forceinline__ bool blk_decode(int& xs, int& yg){
  const int id  = blockIdx.x;
  const int xcd = id & 7;
  const int s   = id >> 3;
  yg = s & (GY-1);                 // GY power of 2
  const int k = s / GY;
  xs = xcd*TPX + k;
  return xs < PXT;
}

// ----------------------------------------------- fast generic conv -------
// 256 thr = 4 waves; 128-px tile (2 px/thread); wave -> NACC out-channels.
template<int CIN,int KH,int KW,int NACC,int GY,int ACT>
__global__ __launch_bounds__(256) void k_fconv(
    const double* __restrict__ in, const double* __restrict__ wt,
    const float* __restrict__ bias, double* __restrict__ out, const int Cout){
  int xs, yg;
  if (!blk_decode<GY>(xs, yg)) return;
  const int lane = threadIdx.x & 63;
  const int wvu  = __builtin_amdgcn_readfirstlane((int)(threadIdx.x >> 6));
  const int ow0  = (yg*4 + wvu)*NACC;
  const int pb   = xs*128;
  const int b    = pb / HW;
  int rr[2], yy[2], xx[2];
  #pragma unroll
  for (int i=0;i<2;++i){
    const int r = pb + i*64 + lane - b*HW;
    rr[i]=r; yy[i]=r/WW; xx[i]=r - (r/WW)*WW;
  }
  double acc[2][NACC];
  #pragma unroll
  for (int j=0;j<NACC;++j){
    const double bj = (double)bias[ow0+j];
    #pragma unroll
    for (int i=0;i<2;++i) acc[i][j]=bj;
  }
  const double* inb = in + (size_t)b*CIN*HW;
  const int TAPS = KH*KW;
  int dy = -(KH/2), dx = -(KW/2);
  #pragma unroll 1
  for (int t=0;t<TAPS;++t){
    int po[2]; bool va[2];
    #pragma unroll
    for (int i=0;i<2;++i){
      const int iy = yy[i]+dy, ix = xx[i]+dx;
      va[i] = ((unsigned)iy < (unsigned)HH) && ((unsigned)ix < (unsigned)WW);
      po[i] = va[i] ? iy*WW+ix : 0;
    }
    const double* wr = wt + (size_t)t*Cout + ow0;
    #pragma unroll 4
    for (int c=0;c<CIN;++c){
      double v[2];
      #pragma unroll
      for (int i=0;i<2;++i) v[i] = va[i] ? inb[(size_t)c*HW + po[i]] : 0.0;
      #pragma unroll
      for (int j=0;j<NACC;++j){
        const double wj = wr[j];
        #pragma unroll
        for (int i=0;i<2;++i) acc[i][j] = fma(v[i], wj, acc[i][j]);
      }
      wr += (size_t)TAPS*Cout;
    }
    if (++dx > KW/2){ dx = -(KW/2); ++dy; }
  }
  #pragma unroll
  for (int j=0;j<NACC;++j)
    #pragma unroll
    for (int i=0;i<2;++i){
      double v = acc[i][j];
      if (ACT==1) v = v > 0.0 ? v : 0.0;
      out[((size_t)b*Cout + ow0 + j)*HW + rr[i]] = v;
    }
}

// -------------------------------------------- GRU conv segment helpers ---
// Two-gate accumulate (z,r over h channels).
template<typename T,int C,int NACC>
__device__ __forceinline__ void fseg2(const T* __restrict__ base,
    const int po[2], const bool va[2],
    const double* __restrict__ wz0, const double* __restrict__ wr0,
    double az[2][NACC], double ar[2][NACC]){
  const double* wz = wz0;
  const double* wr = wr0;
  #pragma unroll 2
  for (int c=0;c<C;++c){
    double v[2];
    #pragma unroll
    for (int i=0;i<2;++i) v[i] = va[i] ? (double)base[(size_t)c*HW + po[i]] : 0.0;
    #pragma unroll
    for (int j=0;j<NACC;++j){
      const double wzj = wz[j], wrj = wr[j];
      #pragma unroll
      for (int i=0;i<2;++i){
        az[i][j] = fma(v[i], wzj, az[i][j]);
        ar[i][j] = fma(v[i], wrj, ar[i][j]);
      }
    }
    wz += 5*HD; wr += 5*HD;
  }
}
// Three-gate accumulate (z,r,qx over d4/ctx channels) — 48 FMA / 2 loads.
template<typename T,int C,int NACC>
__device__ __forceinline__ void fseg3(const T* __restrict__ base,
    const int po[2], const bool va[2],
    const double* __restrict__ wz0, const double* __restrict__ wr0,
    const double* __restrict__ wq0,
    double az[2][NACC], double ar[2][NACC], double aq[2][NACC]){
  const double* wz = wz0;
  const double* wr = wr0;
  const double* wq = wq0;
  #pragma unroll 2
  for (int c=0;c<C;++c){
    double v[2];
    #pragma unroll
    for (int i=0;i<2;++i) v[i] = va[i] ? (double)base[(size_t)c*HW + po[i]] : 0.0;
    #pragma unroll
    for (int j=0;j<NACC;++j){
      const double wzj = wz[j], wrj = wr[j], wqj = wq[j];
      #pragma unroll
      for (int i=0;i<2;++i){
        az[i][j] = fma(v[i], wzj, az[i][j]);
        ar[i][j] = fma(v[i], wrj, ar[i][j]);
        aq[i][j] = fma(v[i], wqj, aq[i][j]);
      }
    }
    wz += 5*HD; wr += 5*HD; wq += 5*HD;
  }
}
// One-gate accumulate (q over rgh channels).
template<typename T,int C,int NACC>
__device__ __forceinline__ void fseg1(const T* __restrict__ base,
    const int po[2], const bool va[2], const double* __restrict__ wq0,
    double aq[2][NACC]){
  const double* wq = wq0;
  #pragma unroll 4
  for (int c=0;c<C;++c){
    double v[2];
    #pragma unroll
    for (int i=0;i<2;++i) v[i] = va[i] ? (double)base[(size_t)c*HW + po[i]] : 0.0;
    #pragma unroll
    for (int j=0;j<NACC;++j){
      const double wj = wq[j];
      #pragma unroll
      for (int i=0;i<2;++i) aq[i][j] = fma(v[i], wj, aq[i][j]);
    }
    wq += 5*HD;
  }
}

// Fused z,r,qx: zg = sigmoid(z_conv); rgh = sigmoid(r_conv)*h;
// qx = bias_q + conv over (d4,ctx) channels of the q weight.
template<int VERT>
__global__ __launch_bounds__(256) void k_fgru_zrx(
    const double* __restrict__ h, const double* __restrict__ d4,
    const float* __restrict__ ctx,
    const double* __restrict__ wtz, const double* __restrict__ wtr,
    const double* __restrict__ wtq,
    const float* __restrict__ bz, const float* __restrict__ br,
    const float* __restrict__ bq,
    double* __restrict__ zg, double* __restrict__ rgh, double* __restrict__ qx){
  const int NACC = 8;
  int xs, yg;
  if (!blk_decode<4>(xs, yg)) return;
  const int lane = threadIdx.x & 63;
  const int wvu  = __builtin_amdgcn_readfirstlane((int)(threadIdx.x >> 6));
  const int ow0  = (yg*4 + wvu)*NACC;       // 0..127
  const int pb   = xs*128;
  const int b    = pb / HW;
  int rr[2], yy[2], xx[2];
  #pragma unroll
  for (int i=0;i<2;++i){
    const int r = pb + i*64 + lane - b*HW;
    rr[i]=r; yy[i]=r/WW; xx[i]=r - (r/WW)*WW;
  }
  double az[2][NACC], ar[2][NACC], aq[2][NACC];
  #pragma unroll
  for (int j=0;j<NACC;++j){
    const double bzj = (double)bz[ow0+j], brj = (double)br[ow0+j], bqj = (double)bq[ow0+j];
    #pragma unroll
    for (int i=0;i<2;++i){ az[i][j]=bzj; ar[i][j]=brj; aq[i][j]=bqj; }
  }
  const double* ab = h  + (size_t)b*HD *HW;
  const double* db = d4 + (size_t)b*OCH*HW;
  const float*  cb = ctx+ (size_t)b*CDC*HW;
  #pragma unroll 1
  for (int t=0;t<5;++t){
    const int dy = VERT ? (t-2) : 0;
    const int dx = VERT ? 0 : (t-2);
    int po[2]; bool va[2];
    #pragma unroll
    for (int i=0;i<2;++i){
      const int iy = yy[i]+dy, ix = xx[i]+dx;
      va[i] = ((unsigned)iy < (unsigned)HH) && ((unsigned)ix < (unsigned)WW);
      po[i] = va[i] ? iy*WW+ix : 0;
    }
    // z,r over h channels (order matches round 6)
    fseg2<double,HD ,NACC>(ab, po, va,
        wtz + ((size_t)0*5 + t)*HD + ow0,  wtr + ((size_t)0*5 + t)*HD + ow0, az, ar);
    // z,r,qx over d4 + ctx channels
    fseg3<double,OCH,NACC>(db, po, va,
        wtz + ((size_t)HD*5 + t)*HD + ow0, wtr + ((size_t)HD*5 + t)*HD + ow0,
        wtq + ((size_t)HD*5 + t)*HD + ow0, az, ar, aq);
    fseg3<float ,CDC,NACC>(cb, po, va,
        wtz + ((size_t)(HD+OCH)*5 + t)*HD + ow0, wtr + ((size_t)(HD+OCH)*5 + t)*HD + ow0,
        wtq + ((size_t)(HD+OCH)*5 + t)*HD + ow0, az, ar, aq);
  }
  #pragma unroll
  for (int j=0;j<NACC;++j)
    #pragma unroll
    for (int i=0;i<2;++i){
      const size_t oi = ((size_t)b*HD + ow0 + j)*HW + rr[i];
      zg[oi]  = 1.0/(1.0+exp(-az[i][j]));
      rgh[oi] = (1.0/(1.0+exp(-ar[i][j]))) * h[oi];
      qx[oi]  = aq[i][j];
    }
}

// q over rgh channels (128 only) + in-place hidden update.
template<int VERT>
__global__ __launch_bounds__(256) void k_fgru_qh(
    const double* __restrict__ rgh, const double* __restrict__ wtq,
    const double* __restrict__ qx, const double* __restrict__ zg,
    double* __restrict__ h){
  const int NACC = 8;
  int xs, yg;
  if (!blk_decode<4>(xs, yg)) return;
  const int lane = threadIdx.x & 63;
  const int wvu  = __builtin_amdgcn_readfirstlane((int)(threadIdx.x >> 6));
  const int ow0  = (yg*4 + wvu)*NACC;
  const int pb   = xs*128;
  const int b    = pb / HW;
  int rr[2], yy[2], xx[2];
  #pragma unroll
  for (int i=0;i<2;++i){
    const int r = pb + i*64 + lane - b*HW;
    rr[i]=r; yy[i]=r/WW; xx[i]=r - (r/WW)*WW;
  }
  double aq[2][NACC];
  #pragma unroll
  for (int j=0;j<NACC;++j)
    #pragma unroll
    for (int i=0;i<2;++i)
      aq[i][j] = qx[((size_t)b*HD + ow0 + j)*HW + rr[i]];
  const double* gb = rgh + (size_t)b*HD*HW;
  #pragma unroll 1
  for (int t=0;t<5;++t){
    const int dy = VERT ? (t-2) : 0;
    const int dx = VERT ? 0 : (t-2);
    int po[2]; bool va[2];
    #pragma unroll
    for (int i=0;i<2;++i){
      const int iy = yy[i]+dy, ix = xx[i]+dx;
      va[i] = ((unsigned)iy < (unsigned)HH) && ((unsigned)ix < (unsigned)WW);
      po[i] = va[i] ? iy*WW+ix : 0;
    }
    fseg1<double,HD,NACC>(gb, po, va, wtq + ((size_t)0*5 + t)*HD + ow0, aq);
  }
  #pragma unroll
  for (int j=0;j<NACC;++j)
    #pragma unroll
    for (int i=0;i<2;++i){
      const size_t oi = ((size_t)b*HD + ow0 + j)*HW + rr[i];
      const double z = zg[oi];
      h[oi] = (1.0-z)*h[oi] + z*tanh(aq[i][j]);
    }
}

// ---- round-6 fallback GRU kernels (used if workspace lacks qx buffer) ----
template<int VERT>
__global__ __launch_bounds__(256) void k_fgru_zr(
    const double* __restrict__ h, const double* __restrict__ d4,
    const float* __restrict__ ctx,
    const double* __restrict__ wtz, const double* __restrict__ wtr,
    const float* __restrict__ bz, const float* __restrict__ br,
    double* __restrict__ zg, double* __restrict__ rgh){
  const int NACC = 8;
  int xs, yg;
  if (!blk_decode<4>(xs, yg)) return;
  const int lane = threadIdx.x & 63;
  const int wvu  = __builtin_amdgcn_readfirstlane((int)(threadIdx.x >> 6));
  const int ow0  = (yg*4 + wvu)*NACC;
  const int pb   = xs*128;
  const int b    = pb / HW;
  int rr[2], yy[2], xx[2];
  #pragma unroll
  for (int i=0;i<2;++i){
    const int r = pb + i*64 + lane - b*HW;
    rr[i]=r; yy[i]=r/WW; xx[i]=r - (r/WW)*WW;
  }
  double az[2][NACC], ar[2][NACC];
  #pragma unroll
  for (int j=0;j<NACC;++j){
    const double bzj = (double)bz[ow0+j], brj = (double)br[ow0+j];
    #pragma unroll
    for (int i=0;i<2;++i){ az[i][j]=bzj; ar[i][j]=brj; }
  }
  const double* ab = h  + (size_t)b*HD *HW;
  const double* db = d4 + (size_t)b*OCH*HW;
  const float*  cb = ctx+ (size_t)b*CDC*HW;
  #pragma unroll 1
  for (int t=0;t<5;++t){
    const int dy = VERT ? (t-2) : 0;
    const int dx = VERT ? 0 : (t-2);
    int po[2]; bool va[2];
    #pragma unroll
    for (int i=0;i<2;++i){
      const int iy = yy[i]+dy, ix = xx[i]+dx;
      va[i] = ((unsigned)iy < (unsigned)HH) && ((unsigned)ix < (unsigned)WW);
      po[i] = va[i] ? iy*WW+ix : 0;
    }
    fseg2<double,HD ,NACC>(ab, po, va,
        wtz + ((size_t)0*5 + t)*HD + ow0,        wtr + ((size_t)0*5 + t)*HD + ow0, az, ar);
    fseg2<double,OCH,NACC>(db, po, va,
        wtz + ((size_t)HD*5 + t)*HD + ow0,       wtr + ((size_t)HD*5 + t)*HD + ow0, az, ar);
    fseg2<float ,CDC,NACC>(cb, po, va,
        wtz + ((size_t)(HD+OCH)*5 + t)*HD + ow0, wtr + ((size_t)(HD+OCH)*5 + t)*HD + ow0, az, ar);
  }
  #pragma unroll
  for (int j=0;j<NACC;++j)
    #pragma unroll
    for (int i=0;i<2;++i){
      const size_t oi = ((size_t)b*HD + ow0 + j)*HW + rr[i];
      zg[oi]  = 1.0/(1.0+exp(-az[i][j]));
      rgh[oi] = (1.0/(1.0+exp(-ar[i][j]))) * h[oi];
    }
}

template<int VERT>
__global__ __launch_bounds__(256) void k_fgru_q(
    const double* __restrict__ rgh, const double* __restrict__ d4,
    const float* __restrict__ ctx, const double* __restrict__ wtq,
    const float* __restrict__ bq, const double* __restrict__ zg,
    double* __restrict__ h){
  const int NACC = 8;
  int xs, yg;
  if (!blk_decode<4>(xs, yg)) return;
  const int lane = threadIdx.x & 63;
  const int wvu  = __builtin_amdgcn_readfirstlane((int)(threadIdx.x >> 6));
  const int ow0  = (yg*4 + wvu)*NACC;
  const int pb   = xs*128;
  const int b    = pb / HW;
  int rr[2], yy[2], xx[2];
  #pragma unroll
  for (int i=0;i<2;++i){
    const int r = pb + i*64 + lane - b*HW;
    rr[i]=r; yy[i]=r/WW; xx[i]=r - (r/WW)*WW;
  }
  double aq[2][NACC];
  #pragma unroll
  for (int j=0;j<NACC;++j){
    const double bj = (double)bq[ow0+j];
    #pragma unroll
    for (int i=0;i<2;++i) aq[i][j]=bj;
  }
  const double* gb = rgh + (size_t)b*HD *HW;
  const double* db = d4  + (size_t)b*OCH*HW;
  const float*  cb = ctx + (size_t)b*CDC*HW;
  #pragma unroll 1
  for (int t=0;t<5;++t){
    const int dy = VERT ? (t-2) : 0;
    const int dx = VERT ? 0 : (t-2);
    int po[2]; bool va[2];
    #pragma unroll
    for (int i=0;i<2;++i){
      const int iy = yy[i]+dy, ix = xx[i]+dx;
      va[i] = ((unsigned)iy < (unsigned)HH) && ((unsigned)ix < (unsigned)WW);
      po[i] = va[i] ? iy*WW+ix : 0;
    }
    fseg1<double,HD ,NACC>(gb, po, va, wtq + ((size_t)0       *5 + t)*HD + ow0, aq);
    fseg1<double,OCH,NACC>(db, po, va, wtq + ((size_t)HD      *5 + t)*HD + ow0, aq);
    fseg1<float ,CDC,NACC>(cb, po, va, wtq + ((size_t)(HD+OCH)*5 + t)*HD + ow0, aq);
  }
  #pragma unroll
  for (int j=0;j<NACC;++j)
    #pragma unroll
    for (int i=0;i<2;++i){
      const size_t oi = ((size_t)b*HD + ow0 + j)*HW + rr[i];
      const double z = zg[oi];
      h[oi] = (1.0-z)*h[oi] + z*tanh(aq[i][j]);
    }
}

// ------------------- softmax + depth_r + unc + label + cs + bin update ----
__global__ __launch_bounds__(256) void k_stats(const double* __restrict__ lg,
    double* __restrict__ edges, double* __restrict__ cd, float* __restrict__ out,
    const int it){
  const int px = blockIdx.x*256 + threadIdx.x;
  const int b = px / HW, r = px - b*HW;
  double l[BN], p[BN], c[BN];
  double m = -1e300;
  #pragma unroll
  for (int k=0;k<BN;++k){ l[k] = lg[(b*BN+k)*HW + r]; m = l[k]>m?l[k]:m; }
  double s = 0.0;
  #pragma unroll
  for (int k=0;k<BN;++k){ p[k] = exp(l[k]-m); s += p[k]; }
  double dr = 0.0;
  #pragma unroll
  for (int k=0;k<BN;++k){ c[k] = cd[(b*BN+k)*HW + r]; p[k] = p[k]/s; dr += p[k]*c[k]; }
  double var = 0.0;
  #pragma unroll
  for (int k=0;k<BN;++k){ const double d = c[k]-dr; var += p[k]*(d*d); }
  const double un = sqrt(var);
  int cnt = 0;
  #pragma unroll
  for (int k=1;k<BN;++k) cnt += (dr >= edges[(b*(BN+1)+k)*HW + r]) ? 1 : 0;
  const double etop = edges[(b*(BN+1)+BN)*HW + r];
  const int label = (dr >= etop) ? 0 : cnt;
  double csv = c[0];
  #pragma unroll
  for (int k=1;k<BN;++k) csv = (label==k) ? c[k] : csv;
  out[((0*6+it)*NB + b)*HW + r] = (float)dr;
  out[((1*6+it)*NB + b)*HW + r] = (float)csv;
  out[((2*6+it)*NB + b)*HW + r] = (float)un;
  const double start = dr - 0.5*un > 0.0 ? dr - 0.5*un : 0.0;
  const double step = un * (1.0/BN);
  double e = start;
  double prev = e < 0.0 ? 0.0 : (e > 80.0 ? 80.0 : e);
  edges[(b*(BN+1)+0)*HW + r] = prev;
  #pragma unroll
  for (int k=1;k<=BN;++k){
    e = e + step;
    const double ec = e < 0.0 ? 0.0 : (e > 80.0 ? 80.0 : e);
    edges[(b*(BN+1)+k)*HW + r] = ec;
    cd[(b*BN + (k-1))*HW + r] = 0.5*(prev + ec);
    prev = ec;
  }
}

// ============================ pipeline ====================================
static void run_all(void* const* d_in, float* out, double* ws, int use_split,
                    hipStream_t stream){
  const float* ctx = (const float*)d_in[1];
  const float* gh  = (const float*)d_in[2];
  const float *e1w=(const float*)d_in[3],  *e1b=(const float*)d_in[4];
  const float *e2w=(const float*)d_in[5],  *e2b=(const float*)d_in[6];
  const float *e3w=(const float*)d_in[7],  *e3b=(const float*)d_in[8];
  const float *e4w=(const float*)d_in[9],  *e4b=(const float*)d_in[10];
  const float *z1w=(const float*)d_in[11], *z1b=(const float*)d_in[12];
  const float *r1w=(const float*)d_in[13], *r1b=(const float*)d_in[14];
  const float *q1w=(const float*)d_in[15], *q1b=(const float*)d_in[16];
  const float *z2w=(const float*)d_in[17], *z2b=(const float*)d_in[18];
  const float *r2w=(const float*)d_in[19], *r2b=(const float*)d_in[20];
  const float *q2w=(const float*)d_in[21], *q2b=(const float*)d_in[22];
  const float *p1w=(const float*)d_in[23], *p1b=(const float*)d_in[24];
  const float *p2w=(const float*)d_in[25], *p2b=(const float*)d_in[26];

  double* h    = ws;
  double* d4   = h    + (size_t)NB*HD*HW;
  double* bufA = d4   + (size_t)NB*OCH*HW;     // zg
  double* bufB = bufA + (size_t)NB*HD*HW;      // rgh
  double* edges= bufB + (size_t)NB*HD*HW;
  double* cd   = edges+ (size_t)NB*(BN+1)*HW;
  double* lgts = cd   + (size_t)NB*BN*HW;
  double* wp   = lgts + (size_t)NB*BN*HW;
  double* we1 = wp;             wp += (size_t)HD*16*49;
  double* we2 = wp;             wp += (size_t)HD*HD*9;
  double* we3 = wp;             wp += (size_t)HD*HD*9;
  double* we4 = wp;             wp += (size_t)OCH*HD*9;
  double* wz1 = wp;             wp += (size_t)HD*GC*5;
  double* wr1 = wp;             wp += (size_t)HD*GC*5;
  double* wq1 = wp;             wp += (size_t)HD*GC*5;
  double* wz2 = wp;             wp += (size_t)HD*GC*5;
  double* wr2 = wp;             wp += (size_t)HD*GC*5;
  double* wq2 = wp;             wp += (size_t)HD*GC*5;
  double* wp1 = wp;             wp += (size_t)HD*HD*9;
  double* wp2 = wp;             wp += (size_t)16*HD*9;
  double* bufC = wp;  // qx, NB*HD*HW doubles (only touched if use_split)

  const dim3 blk(256);

  #define XP(src,dst,Cout_,CIN_,TAPS_) { const int n=(Cout_)*(CIN_)*(TAPS_); \
    k_wxpose<<<dim3((n+255)/256), blk, 0, stream>>>(src, dst, Cout_, CIN_, TAPS_, n); }
  XP(e1w, we1, HD, 16, 49); XP(e2w, we2, HD, HD, 9); XP(e3w, we3, HD, HD, 9);
  XP(e4w, we4, OCH, HD, 9);
  XP(z1w, wz1, HD, GC, 5); XP(r1w, wr1, HD, GC, 5); XP(q1w, wq1, HD, GC, 5);
  XP(z2w, wz2, HD, GC, 5); XP(r2w, wr2, HD, GC, 5); XP(q2w, wq2, HD, GC, 5);
  XP(p1w, wp1, HD, HD, 9); XP(p2w, wp2, 16, HD, 9);
  #undef XP

  k_init<<<dim3((NB*HD*HW+255)/256), blk, 0, stream>>>(gh, h, edges, cd);

  const int G4 = GXP*4;
  const int G8 = GXP*8;
  const int G1 = GXP;
  const int PXB = BHW/256;

  for (int it=0; it<6; ++it){
    k_fconv<16 ,7,7,8,4,1><<<dim3(G4), blk, 0, stream>>>(cd,   we1, e1b, bufA, HD);
    k_fconv<128,3,3,8,4,1><<<dim3(G4), blk, 0, stream>>>(bufA, we2, e2b, bufB, HD);
    k_fconv<128,3,3,8,4,1><<<dim3(G4), blk, 0, stream>>>(bufB, we3, e3b, bufA, HD);
    k_fconv<128,3,3,8,8,1><<<dim3(G8), blk, 0, stream>>>(bufA, we4, e4b, d4,  OCH);
    if (use_split){
      k_fgru_zrx<0><<<dim3(G4), blk, 0, stream>>>(h, d4, ctx, wz1, wr1, wq1,
                                                  z1b, r1b, q1b, bufA, bufB, bufC);
      k_fgru_qh <0><<<dim3(G4), blk, 0, stream>>>(bufB, wq1, bufC, bufA, h);
      k_fgru_zrx<1><<<dim3(G4), blk, 0, stream>>>(h, d4, ctx, wz2, wr2, wq2,
                                                  z2b, r2b, q2b, bufA, bufB, bufC);
      k_fgru_qh <1><<<dim3(G4), blk, 0, stream>>>(bufB, wq2, bufC, bufA, h);
    } else {
      k_fgru_zr<0><<<dim3(G4), blk, 0, stream>>>(h, d4, ctx, wz1, wr1, z1b, r1b, bufA, bufB);
      k_fgru_q <0><<<dim3(G4), blk, 0, stream>>>(bufB, d4, ctx, wq1, q1b, bufA, h);
      k_fgru_zr<1><<<dim3(G4), blk, 0, stream>>>(h, d4, ctx, wz2, wr2, z2b, r2b, bufA, bufB);
      k_fgru_q <1><<<dim3(G4), blk, 0, stream>>>(bufB, d4, ctx, wq2, q2b, bufA, h);
    }
    k_fconv<128,3,3,8,4,1><<<dim3(G4), blk, 0, stream>>>(h,    wp1, p1b, bufA, HD);
    k_fconv<128,3,3,4,1,0><<<dim3(G1), blk, 0, stream>>>(bufA, wp2, p2b, lgts, 16);
    k_stats<<<dim3(PXB), blk, 0, stream>>>(lgts, edges, cd, out, it);
  }
}

// ----------------------------------------------------------- launcher ----
extern "C" void kernel_launch(void* const* d_in, const int* in_sizes, int n_in,
                              void* d_out, int out_size, void* d_ws, size_t ws_size,
                              hipStream_t stream){
  const size_t act_d  = (size_t)NB*(HD + OCH + HD + HD + (BN+1) + BN + BN)*HW;
  const size_t wt_d   = (size_t)HD*16*49 + 3*(size_t)HD*HD*9 + (size_t)OCH*HD*9
                      + 6*(size_t)HD*GC*5 + (size_t)16*HD*9;
  const size_t qx_d   = (size_t)NB*HD*HW;
  const size_t need_split = (act_d + wt_d + qx_d) * sizeof(double);  // ~276 MB
  const size_t need_base  = (act_d + wt_d) * sizeof(double);         // ~236 MB (proven fits)
  if (ws_size >= need_split)
    run_all(d_in, (float*)d_out, (double*)d_ws, 1, stream);
  else if (ws_size >= need_base)
    run_all(d_in, (float*)d_out, (double*)d_ws, 0, stream);
}

// Round 8
// 35213.675 us; speedup vs baseline: 1.3064x; 1.3064x over previous
//
#include <hip/hip_runtime.h>
#include <hip/hip_bf16.h>

// IEBins forward. Round 8: f32 storage + chunked-f32 compute with f64
// master accumulators.
//   Error model: np reference is itself f32 (~1e-5 err on depth_r) and its
//   error band determines the label-flip set (absmax 1.0, passing since r3).
//   Chunked accumulation (f32 FMA over 32-ch chunks, partials start at 0,
//   promoted to f64 masters per chunk) keeps my error ~1e-6 << 1e-5, so the
//   flip set is unchanged. Round-2's failure was naive sequential f32
//   (~1e-4, full-magnitude partials) — NOT f32 per se.
//   f32 weights are lossless (sources f32). f64 FMA floor was the wall
//   (zr dispatch: 1.0 ms floor vs 1.72 measured, VALUBusy 54%).
// Split-q structure (q = conv_h(rgh) + conv_x(x), conv_x folded into the
// z/r kernel) now fits: total workspace ~143 MB (was 276 -> fallback ran
// in round 7, hence the neutral result).

#define HD  128
#define CDC 192
#define BN  16
#define OCH 256
#define GC  576
#define NB  2
#define HH  120
#define WW  160
#define HW  (HH*WW)
#define BHW (NB*HW)
#define PXT (BHW/128)          // 300 pixel tiles of 128 px
#define GXP (((PXT+7)/8)*8)    // 304 padded
#define TPX (GXP/8)            // 38 tiles per XCD slab

// ---------------------------------------------------------------- init ----
__global__ __launch_bounds__(256) void k_init(const float* __restrict__ gh,
        float* __restrict__ h, double* __restrict__ edges, double* __restrict__ cd){
  const int i = blockIdx.x*256 + threadIdx.x;
  const int nh = NB*HD*HW;
  if (i < nh) h[i] = gh[i];
  if (i < BHW){
    const int b = i / HW, r = i - b*HW;
    double e = 0.0;
    #pragma unroll
    for (int k=0;k<BN;++k){
      edges[(b*(BN+1)+k)*HW + r] = e;
      cd[(b*BN+k)*HW + r] = e + 2.5;
      e += 5.0;
    }
    edges[(b*(BN+1)+BN)*HW + r] = e;   // 80
  }
}

// ------------------------------------------------- weight transpose ------
// w[o][c][tap] f32  ->  wt[(c*TAPS+t)*Cout + o] f32 (lossless permutation)
__global__ __launch_bounds__(256) void k_wxpose(const float* __restrict__ w,
        float* __restrict__ wt, const int Cout, const int CIN, const int TAPS,
        const int n){
  const int i = blockIdx.x*256 + threadIdx.x;
  if (i >= n) return;
  const int ct = CIN*TAPS;
  const int o = i / ct;
  const int rem = i - o*ct;
  const int c = rem / TAPS;
  const int t = rem - c*TAPS;
  wt[((size_t)c*TAPS + t)*Cout + o] = w[i];
}

// ------------------------------------------- XCD-aware block decode ------
// id%8 -> XCD; within an XCD: y-groups of one tile adjacent (co-resident),
// tiles consecutive (L2 tap-row reuse). GY must be a power of 2 (or 1).
template<int GY>
__device__ __forceinline__ bool blk_decode(int& xs, int& yg){
  const int id  = blockIdx.x;
  const int xcd = id & 7;
  const int s   = id >> 3;
  yg = s & (GY-1);
  const int k = s / GY;
  xs = xcd*TPX + k;
  return xs < PXT;
}

// ----------------------------------------------- fast generic conv -------
// 256 thr = 4 waves; 128-px tile (2 px/thread); wave -> NACC out-channels.
// Chunked f32 FMA (chunk<=32) into f64 masters.
template<typename TI,int CIN,int KH,int KW,int NACC,int GY,int ACT>
__global__ __launch_bounds__(256) void k_fconv(
    const TI* __restrict__ in, const float* __restrict__ wt,
    const float* __restrict__ bias, float* __restrict__ out, const int Cout){
  int xs, yg;
  if (!blk_decode<GY>(xs, yg)) return;
  const int lane = threadIdx.x & 63;
  const int wvu  = __builtin_amdgcn_readfirstlane((int)(threadIdx.x >> 6));
  const int ow0  = (yg*4 + wvu)*NACC;
  const int pb   = xs*128;
  const int b    = pb / HW;
  int rr[2], yy[2], xx[2];
  #pragma unroll
  for (int i=0;i<2;++i){
    const int r = pb + i*64 + lane - b*HW;
    rr[i]=r; yy[i]=r/WW; xx[i]=r - (r/WW)*WW;
  }
  double acc[2][NACC];
  #pragma unroll
  for (int j=0;j<NACC;++j){
    const double bj = (double)bias[ow0+j];
    #pragma unroll
    for (int i=0;i<2;++i) acc[i][j]=bj;
  }
  const TI* inb = in + (size_t)b*CIN*HW;
  const int TAPS = KH*KW;
  const int CH = (CIN < 32) ? CIN : 32;
  int dy = -(KH/2), dx = -(KW/2);
  #pragma unroll 1
  for (int t=0;t<TAPS;++t){
    int po[2]; bool va[2];
    #pragma unroll
    for (int i=0;i<2;++i){
      const int iy = yy[i]+dy, ix = xx[i]+dx;
      va[i] = ((unsigned)iy < (unsigned)HH) && ((unsigned)ix < (unsigned)WW);
      po[i] = va[i] ? iy*WW+ix : 0;
    }
    #pragma unroll 1
    for (int c0=0;c0<CIN;c0+=CH){
      float ca[2][NACC];
      #pragma unroll
      for (int j=0;j<NACC;++j)
        #pragma unroll
        for (int i=0;i<2;++i) ca[i][j]=0.f;
      const float* wr = wt + ((size_t)c0*TAPS + t)*Cout + ow0;
      #pragma unroll 8
      for (int c=0;c<CH;++c){
        float v[2];
        const size_t cc = (size_t)(c0+c)*HW;
        #pragma unroll
        for (int i=0;i<2;++i) v[i] = va[i] ? (float)inb[cc + po[i]] : 0.f;
        #pragma unroll
        for (int j=0;j<NACC;++j){
          const float wj = wr[j];
          #pragma unroll
          for (int i=0;i<2;++i) ca[i][j] = fmaf(v[i], wj, ca[i][j]);
        }
        wr += (size_t)TAPS*Cout;
      }
      #pragma unroll
      for (int j=0;j<NACC;++j)
        #pragma unroll
        for (int i=0;i<2;++i) acc[i][j] += (double)ca[i][j];
    }
    if (++dx > KW/2){ dx = -(KW/2); ++dy; }
  }
  #pragma unroll
  for (int j=0;j<NACC;++j)
    #pragma unroll
    for (int i=0;i<2;++i){
      double v = acc[i][j];
      if (ACT==1) v = v > 0.0 ? v : 0.0;
      out[((size_t)b*Cout + ow0 + j)*HW + rr[i]] = (float)v;
    }
}

// -------------------------------------------- GRU chunked segments -------
// Two-gate (z,r) chunked accumulate.
template<int C,int NACC>
__device__ __forceinline__ void fseg2c(const float* __restrict__ base,
    const int po[2], const bool va[2],
    const float* __restrict__ wz0, const float* __restrict__ wr0,
    double az[2][NACC], double ar[2][NACC]){
  #pragma unroll 1
  for (int c0=0;c0<C;c0+=32){
    float cz[2][NACC], cr[2][NACC];
    #pragma unroll
    for (int j=0;j<NACC;++j)
      #pragma unroll
      for (int i=0;i<2;++i){ cz[i][j]=0.f; cr[i][j]=0.f; }
    const float* wz = wz0 + (size_t)c0*5*HD;
    const float* wr = wr0 + (size_t)c0*5*HD;
    #pragma unroll 8
    for (int c=0;c<32;++c){
      float v[2];
      const size_t cc = (size_t)(c0+c)*HW;
      #pragma unroll
      for (int i=0;i<2;++i) v[i] = va[i] ? base[cc + po[i]] : 0.f;
      #pragma unroll
      for (int j=0;j<NACC;++j){
        const float wzj = wz[j], wrj = wr[j];
        #pragma unroll
        for (int i=0;i<2;++i){
          cz[i][j] = fmaf(v[i], wzj, cz[i][j]);
          cr[i][j] = fmaf(v[i], wrj, cr[i][j]);
        }
      }
      wz += 5*HD; wr += 5*HD;
    }
    #pragma unroll
    for (int j=0;j<NACC;++j)
      #pragma unroll
      for (int i=0;i<2;++i){ az[i][j]+=(double)cz[i][j]; ar[i][j]+=(double)cr[i][j]; }
  }
}
// Three-gate (z,r,qx) chunked accumulate — 3*NACC*2 FMA per 2 loads.
template<int C,int NACC>
__device__ __forceinline__ void fseg3c(const float* __restrict__ base,
    const int po[2], const bool va[2],
    const float* __restrict__ wz0, const float* __restrict__ wr0,
    const float* __restrict__ wq0,
    double az[2][NACC], double ar[2][NACC], double aq[2][NACC]){
  #pragma unroll 1
  for (int c0=0;c0<C;c0+=32){
    float cz[2][NACC], cr[2][NACC], cq[2][NACC];
    #pragma unroll
    for (int j=0;j<NACC;++j)
      #pragma unroll
      for (int i=0;i<2;++i){ cz[i][j]=0.f; cr[i][j]=0.f; cq[i][j]=0.f; }
    const float* wz = wz0 + (size_t)c0*5*HD;
    const float* wr = wr0 + (size_t)c0*5*HD;
    const float* wq = wq0 + (size_t)c0*5*HD;
    #pragma unroll 8
    for (int c=0;c<32;++c){
      float v[2];
      const size_t cc = (size_t)(c0+c)*HW;
      #pragma unroll
      for (int i=0;i<2;++i) v[i] = va[i] ? base[cc + po[i]] : 0.f;
      #pragma unroll
      for (int j=0;j<NACC;++j){
        const float wzj = wz[j], wrj = wr[j], wqj = wq[j];
        #pragma unroll
        for (int i=0;i<2;++i){
          cz[i][j] = fmaf(v[i], wzj, cz[i][j]);
          cr[i][j] = fmaf(v[i], wrj, cr[i][j]);
          cq[i][j] = fmaf(v[i], wqj, cq[i][j]);
        }
      }
      wz += 5*HD; wr += 5*HD; wq += 5*HD;
    }
    #pragma unroll
    for (int j=0;j<NACC;++j)
      #pragma unroll
      for (int i=0;i<2;++i){
        az[i][j]+=(double)cz[i][j]; ar[i][j]+=(double)cr[i][j]; aq[i][j]+=(double)cq[i][j];
      }
  }
}
// One-gate chunked accumulate.
template<int C,int NACC>
__device__ __forceinline__ void fseg1c(const float* __restrict__ base,
    const int po[2], const bool va[2], const float* __restrict__ wq0,
    double aq[2][NACC]){
  #pragma unroll 1
  for (int c0=0;c0<C;c0+=32){
    float cq[2][NACC];
    #pragma unroll
    for (int j=0;j<NACC;++j)
      #pragma unroll
      for (int i=0;i<2;++i) cq[i][j]=0.f;
    const float* wq = wq0 + (size_t)c0*5*HD;
    #pragma unroll 8
    for (int c=0;c<32;++c){
      float v[2];
      const size_t cc = (size_t)(c0+c)*HW;
      #pragma unroll
      for (int i=0;i<2;++i) v[i] = va[i] ? base[cc + po[i]] : 0.f;
      #pragma unroll
      for (int j=0;j<NACC;++j){
        const float wj = wq[j];
        #pragma unroll
        for (int i=0;i<2;++i) cq[i][j] = fmaf(v[i], wj, cq[i][j]);
      }
      wq += 5*HD;
    }
    #pragma unroll
    for (int j=0;j<NACC;++j)
      #pragma unroll
      for (int i=0;i<2;++i) aq[i][j]+=(double)cq[i][j];
  }
}

// Fused z,r,qx: zg = sigmoid(z_conv); rgh = sigmoid(r_conv)*h;
// qx = bias_q + q-conv over (d4,ctx) channels. NACC=4, GY=8.
template<int VERT>
__global__ __launch_bounds__(256) void k_fgru_zrx(
    const float* __restrict__ h, const float* __restrict__ d4,
    const float* __restrict__ ctx,
    const float* __restrict__ wtz, const float* __restrict__ wtr,
    const float* __restrict__ wtq,
    const float* __restrict__ bz, const float* __restrict__ br,
    const float* __restrict__ bq,
    float* __restrict__ zg, float* __restrict__ rgh, float* __restrict__ qx){
  const int NACC = 4;
  int xs, yg;
  if (!blk_decode<8>(xs, yg)) return;
  const int lane = threadIdx.x & 63;
  const int wvu  = __builtin_amdgcn_readfirstlane((int)(threadIdx.x >> 6));
  const int ow0  = (yg*4 + wvu)*NACC;       // 0..127
  const int pb   = xs*128;
  const int b    = pb / HW;
  int rr[2], yy[2], xx[2];
  #pragma unroll
  for (int i=0;i<2;++i){
    const int r = pb + i*64 + lane - b*HW;
    rr[i]=r; yy[i]=r/WW; xx[i]=r - (r/WW)*WW;
  }
  double az[2][NACC], ar[2][NACC], aq[2][NACC];
  #pragma unroll
  for (int j=0;j<NACC;++j){
    const double bzj=(double)bz[ow0+j], brj=(double)br[ow0+j], bqj=(double)bq[ow0+j];
    #pragma unroll
    for (int i=0;i<2;++i){ az[i][j]=bzj; ar[i][j]=brj; aq[i][j]=bqj; }
  }
  const float* ab = h  + (size_t)b*HD *HW;
  const float* db = d4 + (size_t)b*OCH*HW;
  const float* cb = ctx+ (size_t)b*CDC*HW;
  #pragma unroll 1
  for (int t=0;t<5;++t){
    const int dy = VERT ? (t-2) : 0;
    const int dx = VERT ? 0 : (t-2);
    int po[2]; bool va[2];
    #pragma unroll
    for (int i=0;i<2;++i){
      const int iy = yy[i]+dy, ix = xx[i]+dx;
      va[i] = ((unsigned)iy < (unsigned)HH) && ((unsigned)ix < (unsigned)WW);
      po[i] = va[i] ? iy*WW+ix : 0;
    }
    fseg2c<HD ,NACC>(ab, po, va,
        wtz + ((size_t)0*5 + t)*HD + ow0,  wtr + ((size_t)0*5 + t)*HD + ow0, az, ar);
    fseg3c<OCH,NACC>(db, po, va,
        wtz + ((size_t)HD*5 + t)*HD + ow0, wtr + ((size_t)HD*5 + t)*HD + ow0,
        wtq + ((size_t)HD*5 + t)*HD + ow0, az, ar, aq);
    fseg3c<CDC,NACC>(cb, po, va,
        wtz + ((size_t)(HD+OCH)*5 + t)*HD + ow0, wtr + ((size_t)(HD+OCH)*5 + t)*HD + ow0,
        wtq + ((size_t)(HD+OCH)*5 + t)*HD + ow0, az, ar, aq);
  }
  #pragma unroll
  for (int j=0;j<NACC;++j)
    #pragma unroll
    for (int i=0;i<2;++i){
      const size_t oi = ((size_t)b*HD + ow0 + j)*HW + rr[i];
      zg[oi]  = (float)(1.0/(1.0+exp(-az[i][j])));
      rgh[oi] = (float)((1.0/(1.0+exp(-ar[i][j]))) * (double)h[oi]);
      qx[oi]  = (float)aq[i][j];
    }
}

// q over rgh channels (128) + in-place hidden update. NACC=8, GY=4.
template<int VERT>
__global__ __launch_bounds__(256) void k_fgru_qh(
    const float* __restrict__ rgh, const float* __restrict__ wtq,
    const float* __restrict__ qx, const float* __restrict__ zg,
    float* __restrict__ h){
  const int NACC = 8;
  int xs, yg;
  if (!blk_decode<4>(xs, yg)) return;
  const int lane = threadIdx.x & 63;
  const int wvu  = __builtin_amdgcn_readfirstlane((int)(threadIdx.x >> 6));
  const int ow0  = (yg*4 + wvu)*NACC;
  const int pb   = xs*128;
  const int b    = pb / HW;
  int rr[2], yy[2], xx[2];
  #pragma unroll
  for (int i=0;i<2;++i){
    const int r = pb + i*64 + lane - b*HW;
    rr[i]=r; yy[i]=r/WW; xx[i]=r - (r/WW)*WW;
  }
  double aq[2][NACC];
  #pragma unroll
  for (int j=0;j<NACC;++j)
    #pragma unroll
    for (int i=0;i<2;++i)
      aq[i][j] = (double)qx[((size_t)b*HD + ow0 + j)*HW + rr[i]];
  const float* gb = rgh + (size_t)b*HD*HW;
  #pragma unroll 1
  for (int t=0;t<5;++t){
    const int dy = VERT ? (t-2) : 0;
    const int dx = VERT ? 0 : (t-2);
    int po[2]; bool va[2];
    #pragma unroll
    for (int i=0;i<2;++i){
      const int iy = yy[i]+dy, ix = xx[i]+dx;
      va[i] = ((unsigned)iy < (unsigned)HH) && ((unsigned)ix < (unsigned)WW);
      po[i] = va[i] ? iy*WW+ix : 0;
    }
    fseg1c<HD,NACC>(gb, po, va, wtq + ((size_t)0*5 + t)*HD + ow0, aq);
  }
  #pragma unroll
  for (int j=0;j<NACC;++j)
    #pragma unroll
    for (int i=0;i<2;++i){
      const size_t oi = ((size_t)b*HD + ow0 + j)*HW + rr[i];
      const double z = (double)zg[oi];
      h[oi] = (float)((1.0-z)*(double)h[oi] + z*tanh(aq[i][j]));
    }
}

// ------------------- softmax + depth_r + unc + label + cs + bin update ----
__global__ __launch_bounds__(256) void k_stats(const float* __restrict__ lg,
    double* __restrict__ edges, double* __restrict__ cd, float* __restrict__ out,
    const int it){
  const int px = blockIdx.x*256 + threadIdx.x;
  const int b = px / HW, r = px - b*HW;
  double l[BN], p[BN], c[BN];
  double m = -1e300;
  #pragma unroll
  for (int k=0;k<BN;++k){ l[k] = (double)lg[(b*BN+k)*HW + r]; m = l[k]>m?l[k]:m; }
  double s = 0.0;
  #pragma unroll
  for (int k=0;k<BN;++k){ p[k] = exp(l[k]-m); s += p[k]; }
  double dr = 0.0;
  #pragma unroll
  for (int k=0;k<BN;++k){ c[k] = cd[(b*BN+k)*HW + r]; p[k] = p[k]/s; dr += p[k]*c[k]; }
  double var = 0.0;
  #pragma unroll
  for (int k=0;k<BN;++k){ const double d = c[k]-dr; var += p[k]*(d*d); }
  const double un = sqrt(var);
  int cnt = 0;
  #pragma unroll
  for (int k=1;k<BN;++k) cnt += (dr >= edges[(b*(BN+1)+k)*HW + r]) ? 1 : 0;
  const double etop = edges[(b*(BN+1)+BN)*HW + r];
  const int label = (dr >= etop) ? 0 : cnt;
  double csv = c[0];
  #pragma unroll
  for (int k=1;k<BN;++k) csv = (label==k) ? c[k] : csv;
  out[((0*6+it)*NB + b)*HW + r] = (float)dr;
  out[((1*6+it)*NB + b)*HW + r] = (float)csv;
  out[((2*6+it)*NB + b)*HW + r] = (float)un;
  const double start = dr - 0.5*un > 0.0 ? dr - 0.5*un : 0.0;
  const double step = un * (1.0/BN);
  double e = start;
  double prev = e < 0.0 ? 0.0 : (e > 80.0 ? 80.0 : e);
  edges[(b*(BN+1)+0)*HW + r] = prev;
  #pragma unroll
  for (int k=1;k<=BN;++k){
    e = e + step;
    const double ec = e < 0.0 ? 0.0 : (e > 80.0 ? 80.0 : e);
    edges[(b*(BN+1)+k)*HW + r] = ec;
    cd[(b*BN + (k-1))*HW + r] = 0.5*(prev + ec);
    prev = ec;
  }
}

// ----------------------------------------------------------- launcher ----
extern "C" void kernel_launch(void* const* d_in, const int* in_sizes, int n_in,
                              void* d_out, int out_size, void* d_ws, size_t ws_size,
                              hipStream_t stream){
  const float* ctx = (const float*)d_in[1];
  const float* gh  = (const float*)d_in[2];
  const float *e1w=(const float*)d_in[3],  *e1b=(const float*)d_in[4];
  const float *e2w=(const float*)d_in[5],  *e2b=(const float*)d_in[6];
  const float *e3w=(const float*)d_in[7],  *e3b=(const float*)d_in[8];
  const float *e4w=(const float*)d_in[9],  *e4b=(const float*)d_in[10];
  const float *z1w=(const float*)d_in[11], *z1b=(const float*)d_in[12];
  const float *r1w=(const float*)d_in[13], *r1b=(const float*)d_in[14];
  const float *q1w=(const float*)d_in[15], *q1b=(const float*)d_in[16];
  const float *z2w=(const float*)d_in[17], *z2b=(const float*)d_in[18];
  const float *r2w=(const float*)d_in[19], *r2b=(const float*)d_in[20];
  const float *q2w=(const float*)d_in[21], *q2b=(const float*)d_in[22];
  const float *p1w=(const float*)d_in[23], *p1b=(const float*)d_in[24];
  const float *p2w=(const float*)d_in[25], *p2b=(const float*)d_in[26];
  float* out = (float*)d_out;

  // doubles first (alignment), then floats
  double* edges = (double*)d_ws;                       // NB*17*HW
  double* cd    = edges + (size_t)NB*(BN+1)*HW;        // NB*16*HW
  float*  fb    = (float*)(cd + (size_t)NB*BN*HW);
  float* h    = fb;                                    // NB*128*HW
  float* d4   = h    + (size_t)NB*HD*HW;               // NB*256*HW
  float* bufA = d4   + (size_t)NB*OCH*HW;              // zg
  float* bufB = bufA + (size_t)NB*HD*HW;               // rgh
  float* bufC = bufB + (size_t)NB*HD*HW;               // qx
  float* lgts = bufC + (size_t)NB*HD*HW;               // NB*16*HW
  float* wp   = lgts + (size_t)NB*BN*HW;
  float* we1 = wp;              wp += (size_t)HD*16*49;
  float* we2 = wp;              wp += (size_t)HD*HD*9;
  float* we3 = wp;              wp += (size_t)HD*HD*9;
  float* we4 = wp;              wp += (size_t)OCH*HD*9;
  float* wz1 = wp;              wp += (size_t)HD*GC*5;
  float* wr1 = wp;              wp += (size_t)HD*GC*5;
  float* wq1 = wp;              wp += (size_t)HD*GC*5;
  float* wz2 = wp;              wp += (size_t)HD*GC*5;
  float* wr2 = wp;              wp += (size_t)HD*GC*5;
  float* wq2 = wp;              wp += (size_t)HD*GC*5;
  float* wp1 = wp;              wp += (size_t)HD*HD*9;
  float* wp2 = wp;              wp += (size_t)16*HD*9;

  const dim3 blk(256);

  #define XP(src,dst,Cout_,CIN_,TAPS_) { const int n=(Cout_)*(CIN_)*(TAPS_); \
    k_wxpose<<<dim3((n+255)/256), blk, 0, stream>>>(src, dst, Cout_, CIN_, TAPS_, n); }
  XP(e1w, we1, HD, 16, 49); XP(e2w, we2, HD, HD, 9); XP(e3w, we3, HD, HD, 9);
  XP(e4w, we4, OCH, HD, 9);
  XP(z1w, wz1, HD, GC, 5); XP(r1w, wr1, HD, GC, 5); XP(q1w, wq1, HD, GC, 5);
  XP(z2w, wz2, HD, GC, 5); XP(r2w, wr2, HD, GC, 5); XP(q2w, wq2, HD, GC, 5);
  XP(p1w, wp1, HD, HD, 9); XP(p2w, wp2, 16, HD, 9);
  #undef XP

  k_init<<<dim3((NB*HD*HW+255)/256), blk, 0, stream>>>(gh, h, edges, cd);

  const int G8 = GXP*8, G4 = GXP*4, G1 = GXP;
  const int PXB = BHW/256;

  for (int it=0; it<6; ++it){
    // encoder (e1 reads f64 cd)
    k_fconv<double,16 ,7,7,8,4,1><<<dim3(G4), blk, 0, stream>>>(cd,   we1, e1b, bufA, HD);
    k_fconv<float ,128,3,3,8,4,1><<<dim3(G4), blk, 0, stream>>>(bufA, we2, e2b, bufB, HD);
    k_fconv<float ,128,3,3,8,4,1><<<dim3(G4), blk, 0, stream>>>(bufB, we3, e3b, bufA, HD);
    k_fconv<float ,128,3,3,8,8,1><<<dim3(G8), blk, 0, stream>>>(bufA, we4, e4b, d4,  OCH);
    // horizontal GRU: fused z+r+qx, then q_h + hidden update
    k_fgru_zrx<0><<<dim3(G8), blk, 0, stream>>>(h, d4, ctx, wz1, wr1, wq1,
                                                z1b, r1b, q1b, bufA, bufB, bufC);
    k_fgru_qh <0><<<dim3(G4), blk, 0, stream>>>(bufB, wq1, bufC, bufA, h);
    // vertical GRU
    k_fgru_zrx<1><<<dim3(G8), blk, 0, stream>>>(h, d4, ctx, wz2, wr2, wq2,
                                                z2b, r2b, q2b, bufA, bufB, bufC);
    k_fgru_qh <1><<<dim3(G4), blk, 0, stream>>>(bufB, wq2, bufC, bufA, h);
    // PHead
    k_fconv<float,128,3,3,8,4,1><<<dim3(G4), blk, 0, stream>>>(h,    wp1, p1b, bufA, HD);
    k_fconv<float,128,3,3,4,1,0><<<dim3(G1), blk, 0, stream>>>(bufA, wp2, p2b, lgts, 16);
    k_stats<<<dim3(PXB), blk, 0, stream>>>(lgts, edges, cd, out, it);
  }
}